// Round 6
// baseline (194.311 us; speedup 1.0000x reference)
//
#include <hip/hip_runtime.h>

// Problem constants: N=50000, E=100000, F=80000, B=64, S=32, T=32, D=3
#define NB      64
#define SS      32
#define TT      32
#define RADIUSF 1.1f
#define NC      16              // chunks per graph -> 64*16 = 1024 blocks
#define CAP     512             // scan window == compaction capacity (overflow-safe)
#define NROWS   34              // delta bins: s* in [0,32], s*+1 in [1,33]

// ---------- node heights nh[n*32 + t] ----------
__global__ __launch_bounds__(256) void k_nh(
    const float* __restrict__ x, const float* __restrict__ v,
    float* __restrict__ nh, int Nn)
{
    const int idx = blockIdx.x * 256 + threadIdx.x;
    if (idx >= Nn * TT) return;
    const int n = idx >> 5, t = idx & 31;
    nh[idx] = x[3 * n] * v[t] + x[3 * n + 1] * v[TT + t] + x[3 * n + 2] * v[2 * TT + t];
}

// ---------- edge/face meta: efi = {i0,i1,i2, bits(w_signed)}, efb = graph id ----------
__global__ __launch_bounds__(256) void k_meta(
    const float* __restrict__ nw, const int* __restrict__ ei,
    const int* __restrict__ fc, const int* __restrict__ batch,
    int4* __restrict__ efi, int* __restrict__ efb, int E, int F)
{
    const int j = blockIdx.x * 256 + threadIdx.x;
    if (j >= E + F) return;
    int i0, i1, i2; float w;
    if (j < E) {                       // edge: subtract, min over 2 (i2=i0)
        i0 = ei[j]; i1 = ei[E + j]; i2 = i0;
        w = -fmaxf(nw[i0], nw[i1]);
    } else {                           // face: add, min over 3
        const int f = j - E;
        i0 = fc[f]; i1 = fc[F + f]; i2 = fc[2 * F + f];
        w = fmaxf(nw[i0], fmaxf(nw[i1], nw[i2]));
    }
    efi[j] = make_int4(i0, i1, i2, __float_as_int(w));
    efb[j] = batch[i0];
}

// ---------- node ranges ----------
__global__ void k_ranges(const int* __restrict__ batch, int* __restrict__ ns, int Nn)
{
    const int b = threadIdx.x;
    if (b > NB) return;
    int lo = 0, hi = Nn;
    while (lo < hi) { const int mid = (lo + hi) >> 1; if (batch[mid] < b) lo = mid + 1; else hi = mid; }
    ns[b] = lo;
}

// ---------- main: per-wave private delta histogram, no atomics, no conflicts ----------
__global__ __launch_bounds__(256) void k_main(
    const float* __restrict__ nh, const float* __restrict__ nw,
    const int4* __restrict__ efi, const int* __restrict__ efb,
    const int* __restrict__ ns, float* __restrict__ partial, int EF)
{
    __shared__ float hist[4][NROWS * 64];   // per-wave private [s][lane]
    __shared__ int list[CAP];
    __shared__ int cnt;

    const int tid  = threadIdx.x;
    const int wave = tid >> 6;
    const int lane = tid & 63;
    const int t    = lane & 31;
    const int half = lane >> 5;             // which of 2 simplexes this lane serves
    const int b     = blockIdx.x >> 4;      // / NC
    const int chunk = blockIdx.x & (NC - 1);

    float* H = hist[wave];
    for (int i = tid; i < 4 * NROWS * 64; i += 256) ((float*)hist)[i] = 0.0f;
    __syncthreads();

    const float INV = 31.0f / 2.2f;         // 1/step
    const float DLT = 2.2f / 31.0f;         // step

    // per-(h,w) delta update: 2 LDS RMWs on lane-private column.
    // s* = rint((h+R)/step); sigma* = 1/(1+exp(500*(h - lin[s*])));
    // lin[s*] = s**step - R  =>  h - lin[s*] = (h + R) - s**step
    // delta[s*] += w*sigma*, delta[s*+1] += w*(1 - sigma*)
#define BODY(hv, wv)                                                        \
    {                                                                       \
        float hr = hv + RADIUSF;                                            \
        float sf = rintf(hr * INV);                                         \
        sf = fminf(fmaxf(sf, 0.0f), 32.0f);                                 \
        float t1 = __builtin_fmaf(sf, -DLT, hr);        /* h - lin[s*] */   \
        float Ee = __expf(500.0f * t1);                                     \
        float sg = __builtin_amdgcn_rcpf(1.0f + Ee);                        \
        float dA = wv * sg;                                                 \
        float dB = wv - dA;                                                 \
        float* p = H + (int)sf * 64 + lane;                                 \
        p[0]  += dA;                                                        \
        p[64] += dB;                                                        \
    }

    // ---- nodes of graph b (contiguous, chunk slice, striped over 4 waves) ----
    const int nb0 = ns[b], nb1 = ns[b + 1];
    const int cn  = nb1 - nb0;
    const int u0  = nb0 + (int)(((long long)cn * chunk) / NC);
    const int u1  = nb0 + (int)(((long long)cn * (chunk + 1)) / NC);
    for (int base = u0 + wave * 2; base < u1; base += 8) {
        int n = base + half;
        const bool valid = (n < u1);
        if (!valid) n = base;
        const float h = nh[n * 32 + t];
        const float w = nw[n];
        if (valid) BODY(h, w)
    }

    // ---- edges+faces: scan efb slice, compact matches, process 2/wave-iter ----
    const int e0 = (int)(((long long)EF * chunk) / NC);
    const int e1 = (int)(((long long)EF * (chunk + 1)) / NC);
    for (int wbase = e0; wbase < e1; wbase += CAP) {
        __syncthreads();
        if (tid == 0) cnt = 0;
        __syncthreads();
        const int take = min(CAP, e1 - wbase);
        for (int j = tid; j < take; j += 256)
            if (efb[wbase + j] == b) list[atomicAdd(&cnt, 1)] = wbase + j;
        __syncthreads();
        const int nm = cnt;
        for (int k = wave * 2; k < nm; k += 8) {
            const int kk = k + half;
            const bool valid = (kk < nm);
            const int idx = list[valid ? kk : k];
            const int4 q = efi[idx];
            const float h = fminf(nh[q.x * 32 + t],
                            fminf(nh[q.y * 32 + t], nh[q.z * 32 + t]));
            const float w = __int_as_float(q.w);
            if (valid) BODY(h, w)
        }
    }
#undef BODY

    __syncthreads();
    // flush: partial[block][s*32+t2] = sum over 4 waves and the 2 lane-halves
    float* dst = partial + ((size_t)blockIdx.x << 10);
    for (int i = tid; i < SS * TT; i += 256) {
        const int s = i >> 5, t2 = i & 31;
        float acc = 0.0f;
#pragma unroll
        for (int wv = 0; wv < 4; ++wv)
            acc += hist[wv][s * 64 + t2] + hist[wv][s * 64 + t2 + 32];
        dst[i] = acc;
    }
}

// ---------- reduce over chunks + prefix over s -> out[b][s][t] ----------
__global__ __launch_bounds__(256) void k_finish(
    const float* __restrict__ partial, float* __restrict__ out)
{
    const int idx = blockIdx.x * 256 + threadIdx.x;   // 0..2047
    if (idx >= NB * TT) return;
    const int b = idx >> 5, t = idx & 31;
    const float* src = partial + (((size_t)b * NC) << 10) + t;
    float run = 0.0f;
#pragma unroll
    for (int s = 0; s < SS; ++s) {
        float acc = 0.0f;
#pragma unroll
        for (int c = 0; c < NC; ++c) acc += src[(c << 10) + (s << 5)];
        run += acc;
        out[(b * SS + s) * TT + t] = run;
    }
}

extern "C" void kernel_launch(void* const* d_in, const int* in_sizes, int n_in,
                              void* d_out, int out_size, void* d_ws, size_t ws_size,
                              hipStream_t stream)
{
    const float* x     = (const float*)d_in[0];
    const float* nw    = (const float*)d_in[1];
    const float* v     = (const float*)d_in[2];
    const float* lin   = (const float*)d_in[3]; (void)lin;
    const int*   ei    = (const int*)d_in[4];
    const int*   fc    = (const int*)d_in[5];
    const int*   batch = (const int*)d_in[6];
    float*       out   = (float*)d_out;

    const int Nn = in_sizes[1];
    const int E  = in_sizes[4] / 2;
    const int F  = in_sizes[5] / 3;
    const int EF = E + F;

    auto align256 = [](size_t v_) { return (v_ + 255) & ~(size_t)255; };
    const size_t nh_b  = align256((size_t)Nn * TT * sizeof(float));      // 6.4 MB
    const size_t efi_b = align256((size_t)EF * sizeof(int4));            // 2.9 MB
    const size_t efb_b = align256((size_t)EF * sizeof(int));             // 0.72 MB
    const size_t ns_b  = align256((size_t)(NB + 1) * sizeof(int));
    // partial: NB*NC*1024 floats = 4 MB

    float* nh      = (float*)d_ws;
    int4*  efi     = (int4*)((char*)d_ws + nh_b);
    int*   efb     = (int*)((char*)d_ws + nh_b + efi_b);
    int*   ns      = (int*)((char*)d_ws + nh_b + efi_b + efb_b);
    float* partial = (float*)((char*)d_ws + nh_b + efi_b + efb_b + ns_b);

    k_nh    <<<(Nn * TT + 255) / 256, 256, 0, stream>>>(x, v, nh, Nn);
    k_meta  <<<(EF + 255) / 256,      256, 0, stream>>>(nw, ei, fc, batch, efi, efb, E, F);
    k_ranges<<<1, 128, 0, stream>>>(batch, ns, Nn);
    k_main  <<<NB * NC, 256, 0, stream>>>(nh, nw, efi, efb, ns, partial, EF);
    k_finish<<<(NB * TT + 255) / 256, 256, 0, stream>>>(partial, out);
}

// Round 7
// 94.629 us; speedup vs baseline: 2.0534x; 2.0534x over previous
//
#include <hip/hip_runtime.h>

// Problem constants: N=50000, E=100000, F=80000, B=64, S=32, T=32, D=3
#define NB      64
#define SS      32
#define TT      32
#define RADIUSF 1.1f
#define NC      16              // chunks per graph -> 64*16 = 1024 blocks
#define CAP     2048            // scan window == compaction capacity
#define NROWS   34              // delta bins: s* in [0,32], s*+1 in [1,33]

// ---------- node heights nh[n*32 + t] ----------
__global__ __launch_bounds__(256) void k_nh(
    const float* __restrict__ x, const float* __restrict__ v,
    float* __restrict__ nh, int Nn)
{
    const int idx = blockIdx.x * 256 + threadIdx.x;
    if (idx >= Nn * TT) return;
    const int n = idx >> 5, t = idx & 31;
    nh[idx] = x[3 * n] * v[t] + x[3 * n + 1] * v[TT + t] + x[3 * n + 2] * v[2 * TT + t];
}

// ---------- edge/face meta: efi = {i0,i1,i2, bits(w_signed)}, efb = graph id ----------
__global__ __launch_bounds__(256) void k_meta(
    const float* __restrict__ nw, const int* __restrict__ ei,
    const int* __restrict__ fc, const int* __restrict__ batch,
    int4* __restrict__ efi, int* __restrict__ efb, int E, int F)
{
    const int j = blockIdx.x * 256 + threadIdx.x;
    if (j >= E + F) return;
    int i0, i1, i2; float w;
    if (j < E) {                       // edge: subtract, min over 2 (i2=i0)
        i0 = ei[j]; i1 = ei[E + j]; i2 = i0;
        w = -fmaxf(nw[i0], nw[i1]);
    } else {                           // face: add, min over 3
        const int f = j - E;
        i0 = fc[f]; i1 = fc[F + f]; i2 = fc[2 * F + f];
        w = fmaxf(nw[i0], fmaxf(nw[i1], nw[i2]));
    }
    efi[j] = make_int4(i0, i1, i2, __float_as_int(w));
    efb[j] = batch[i0];
}

// ---------- node ranges ----------
__global__ void k_ranges(const int* __restrict__ batch, int* __restrict__ ns, int Nn)
{
    const int b = threadIdx.x;
    if (b > NB) return;
    int lo = 0, hi = Nn;
    while (lo < hi) { const int mid = (lo + hi) >> 1; if (batch[mid] < b) lo = mid + 1; else hi = mid; }
    ns[b] = lo;
}

// ---------- main: per-wave private delta histogram, no atomics, no conflicts ----------
__global__ __launch_bounds__(256) void k_main(
    const float* __restrict__ nh, const float* __restrict__ nw,
    const int4* __restrict__ efi, const int* __restrict__ efb,
    const int* __restrict__ ns, float* __restrict__ partial, int EF)
{
    __shared__ float hist[4][NROWS * 64];   // per-wave private [s][lane]
    __shared__ int list[CAP];
    __shared__ int cnt;

    const int tid  = threadIdx.x;
    const int wave = tid >> 6;
    const int lane = tid & 63;
    const int t    = lane & 31;
    const int half = lane >> 5;             // which of 2 simplexes this lane serves
    const int b     = blockIdx.x >> 4;      // / NC
    const int chunk = blockIdx.x & (NC - 1);

    float* H = hist[wave];
    for (int i = tid; i < 4 * NROWS * 64; i += 256) ((float*)hist)[i] = 0.0f;
    __syncthreads();

    const float INV = 31.0f / 2.2f;         // 1/step
    const float DLT = 2.2f / 31.0f;         // step

    // per-(h,w) delta update: 2 LDS RMWs on lane-private column.
    // s* = rint((h+R)/step); sigma* = 1/(1+exp(500*(h - lin[s*])));
    // lin[s*] = s**step - R  =>  h - lin[s*] = (h + R) - s**step
#define BODY(hv, wv)                                                        \
    {                                                                       \
        float hr = hv + RADIUSF;                                            \
        float sf = rintf(hr * INV);                                         \
        sf = fminf(fmaxf(sf, 0.0f), 32.0f);                                 \
        float t1 = __builtin_fmaf(sf, -DLT, hr);        /* h - lin[s*] */   \
        float Ee = __expf(500.0f * t1);                                     \
        float sg = __builtin_amdgcn_rcpf(1.0f + Ee);                        \
        float dA = wv * sg;                                                 \
        float dB = wv - dA;                                                 \
        float* p = H + (int)sf * 64 + lane;                                 \
        p[0]  += dA;                                                        \
        p[64] += dB;                                                        \
    }

    // ---- nodes of graph b (contiguous, chunk slice, striped over 4 waves) ----
    const int nb0 = ns[b], nb1 = ns[b + 1];
    const int cn  = nb1 - nb0;
    const int u0  = nb0 + (int)(((long long)cn * chunk) / NC);
    const int u1  = nb0 + (int)(((long long)cn * (chunk + 1)) / NC);
    for (int base = u0 + wave * 2; base < u1; base += 8) {
        int n = base + half;
        const bool valid = (n < u1);
        if (!valid) n = base;
        const float h = nh[n * 32 + t];
        const float w = nw[n];
        if (valid) BODY(h, w)
    }

    // ---- edges+faces: scan efb slice, compact matches, process 8/block-iter ----
    const int e0 = (int)(((long long)EF * chunk) / NC);
    const int e1 = (int)(((long long)EF * (chunk + 1)) / NC);
    for (int wbase = e0; wbase < e1; wbase += CAP) {
        __syncthreads();
        if (tid == 0) cnt = 0;
        __syncthreads();
        const int take = min(CAP, e1 - wbase);
        for (int j = tid; j < take; j += 256)
            if (efb[wbase + j] == b) list[atomicAdd(&cnt, 1)] = wbase + j;
        __syncthreads();
        const int nm = cnt;
        for (int k = wave * 2; k < nm; k += 8) {
            const int kk = k + half;
            const bool valid = (kk < nm);
            const int idx = list[valid ? kk : k];
            const int4 q = efi[idx];
            const float h = fminf(nh[q.x * 32 + t],
                            fminf(nh[q.y * 32 + t], nh[q.z * 32 + t]));
            const float w = __int_as_float(q.w);
            if (valid) BODY(h, w)
        }
    }
#undef BODY

    __syncthreads();
    // flush: partial[block][s*32+t2] = sum over 4 waves and the 2 lane-halves
    float* dst = partial + ((size_t)blockIdx.x << 10);
    for (int i = tid; i < SS * TT; i += 256) {
        const int s = i >> 5, t2 = i & 31;
        float acc = 0.0f;
#pragma unroll
        for (int wv = 0; wv < 4; ++wv)
            acc += hist[wv][s * 64 + t2] + hist[wv][s * 64 + t2 + 32];
        dst[i] = acc;
    }
}

// ---------- finish: one block per graph; reduce chunks + prefix over s ----------
__global__ __launch_bounds__(1024) void k_finish(
    const float* __restrict__ partial, float* __restrict__ out)
{
    __shared__ float tile[SS * TT];
    const int b   = blockIdx.x;
    const int tid = threadIdx.x;            // cell = s*32 + t
    const float* src = partial + (((size_t)b * NC) << 10) + tid;
    float acc = 0.0f;
#pragma unroll
    for (int c = 0; c < NC; ++c) acc += src[(size_t)c << 10];
    tile[tid] = acc;
    __syncthreads();
    const int t = tid & 31, s = tid >> 5;
    float run = 0.0f;
    for (int sp = 0; sp <= s; ++sp) run += tile[(sp << 5) + t];
    out[((size_t)b << 10) + tid] = run;
}

extern "C" void kernel_launch(void* const* d_in, const int* in_sizes, int n_in,
                              void* d_out, int out_size, void* d_ws, size_t ws_size,
                              hipStream_t stream)
{
    const float* x     = (const float*)d_in[0];
    const float* nw    = (const float*)d_in[1];
    const float* v     = (const float*)d_in[2];
    const float* lin   = (const float*)d_in[3]; (void)lin;
    const int*   ei    = (const int*)d_in[4];
    const int*   fc    = (const int*)d_in[5];
    const int*   batch = (const int*)d_in[6];
    float*       out   = (float*)d_out;

    const int Nn = in_sizes[1];
    const int E  = in_sizes[4] / 2;
    const int F  = in_sizes[5] / 3;
    const int EF = E + F;

    auto align256 = [](size_t v_) { return (v_ + 255) & ~(size_t)255; };
    const size_t nh_b  = align256((size_t)Nn * TT * sizeof(float));      // 6.4 MB
    const size_t efi_b = align256((size_t)EF * sizeof(int4));            // 2.9 MB
    const size_t efb_b = align256((size_t)EF * sizeof(int));             // 0.72 MB
    const size_t ns_b  = align256((size_t)(NB + 1) * sizeof(int));
    // partial: NB*NC*1024 floats = 4 MB

    float* nh      = (float*)d_ws;
    int4*  efi     = (int4*)((char*)d_ws + nh_b);
    int*   efb     = (int*)((char*)d_ws + nh_b + efi_b);
    int*   ns      = (int*)((char*)d_ws + nh_b + efi_b + efb_b);
    float* partial = (float*)((char*)d_ws + nh_b + efi_b + efb_b + ns_b);

    k_nh    <<<(Nn * TT + 255) / 256, 256, 0, stream>>>(x, v, nh, Nn);
    k_meta  <<<(EF + 255) / 256,      256, 0, stream>>>(nw, ei, fc, batch, efi, efb, E, F);
    k_ranges<<<1, 128, 0, stream>>>(batch, ns, Nn);
    k_main  <<<NB * NC, 256, 0, stream>>>(nh, nw, efi, efb, ns, partial, EF);
    k_finish<<<NB, 1024, 0, stream>>>(partial, out);
}

// Round 8
// 72.841 us; speedup vs baseline: 2.6676x; 1.2991x over previous
//
#include <hip/hip_runtime.h>

// Problem constants: N=50000, E=100000, F=80000, B=64, S=32, T=32, D=3
#define NB      64
#define SS      32
#define TT      32
#define RADIUSF 1.1f
#define NC      16              // chunks per graph -> grid = 16*64 = 1024 = 4 blocks/CU exactly
#define NROWS   34              // delta bins: s* in [0,32], s*+1 in [1,33]
#define NCNT    128             // blocks for count/scatter passes

// ---------- node heights nh[n*32 + t] ----------
__global__ __launch_bounds__(256) void k_nh(
    const float* __restrict__ x, const float* __restrict__ v,
    float* __restrict__ nh, int Nn)
{
    const int idx = blockIdx.x * 256 + threadIdx.x;
    if (idx >= Nn * TT) return;
    const int n = idx >> 5, t = idx & 31;
    nh[idx] = x[3 * n] * v[t] + x[3 * n + 1] * v[TT + t] + x[3 * n + 2] * v[2 * TT + t];
}

// ---------- count edges/faces per graph ----------
__global__ __launch_bounds__(256) void k_count(
    const int* __restrict__ ei, const int* __restrict__ fc,
    const int* __restrict__ batch, int* __restrict__ gcnt, int E, int F)
{
    __shared__ int lc[NB];
    const int tid = threadIdx.x;
    const int EF = E + F;
    if (tid < NB) lc[tid] = 0;
    __syncthreads();
    const int j0 = (int)((long long)EF * blockIdx.x / gridDim.x);
    const int j1 = (int)((long long)EF * (blockIdx.x + 1) / gridDim.x);
    for (int j = j0 + tid; j < j1; j += 256) {
        const int i0 = (j < E) ? ei[j] : fc[j - E];
        atomicAdd(&lc[batch[i0]], 1);
    }
    __syncthreads();
    if (tid < NB && lc[tid]) atomicAdd(&gcnt[tid], lc[tid]);
}

// ---------- prefix: graph node-ranges + bucket bases; zero cur ----------
__global__ __launch_bounds__(256) void k_prefix(
    const int* __restrict__ batch, const int* __restrict__ gcnt,
    int* __restrict__ ns, int* __restrict__ ubase, int* __restrict__ ebase,
    int* __restrict__ cur, int Nn)
{
    __shared__ int s_ns[NB + 1];
    __shared__ int s_base[NB + 1];
    const int tid = threadIdx.x;
    if (tid <= NB) {
        int lo = 0, hi = Nn;
        while (lo < hi) { const int mid = (lo + hi) >> 1; if (batch[mid] < tid) lo = mid + 1; else hi = mid; }
        s_ns[tid] = lo;
    }
    __syncthreads();
    if (tid == 0) {
        int run = 0;
        for (int b = 0; b < NB; ++b) { s_base[b] = run; run += gcnt[b]; }
        s_base[NB] = run;
    }
    __syncthreads();
    if (tid <= NB) { ns[tid] = s_ns[tid]; ubase[tid] = s_ns[tid] + s_base[tid]; }
    if (tid < NB)  { ebase[tid] = s_ns[tid + 1] + s_base[tid]; cur[tid] = 0; }
}

// ---------- scatter: build unified graph-sorted simplex array U ----------
__global__ __launch_bounds__(256) void k_scatter(
    const float* __restrict__ nw, const int* __restrict__ ei,
    const int* __restrict__ fc, const int* __restrict__ batch,
    const int* __restrict__ ns, const int* __restrict__ ubase,
    const int* __restrict__ ebase, int* __restrict__ cur,
    int4* __restrict__ U, int Nn, int E, int F)
{
    __shared__ int lc[NB];
    __shared__ int lb[NB];
    const int tid = threadIdx.x;
    const int M = Nn + E + F;
    const int m0 = (int)((long long)M * blockIdx.x / gridDim.x);
    const int m1 = (int)((long long)M * (blockIdx.x + 1) / gridDim.x);
    if (tid < NB) lc[tid] = 0;
    __syncthreads();
    // pass A: write nodes directly (deterministic slots); count edges/faces
    for (int m = m0 + tid; m < m1; m += 256) {
        if (m < Nn) {
            const int b = batch[m];
            U[ubase[b] + (m - ns[b])] = make_int4(m, m, m, __float_as_int(nw[m]));
        } else {
            const int j = m - Nn;
            const int i0 = (j < E) ? ei[j] : fc[j - E];
            atomicAdd(&lc[batch[i0]], 1);
        }
    }
    __syncthreads();
    if (tid < NB) { const int c = lc[tid]; lb[tid] = c ? atomicAdd(&cur[tid], c) : 0; lc[tid] = 0; }
    __syncthreads();
    // pass B: write edges/faces at reserved slots
    for (int m = m0 + tid; m < m1; m += 256) {
        if (m >= Nn) {
            const int j = m - Nn;
            int i0, i1, i2; float w;
            if (j < E) {
                i0 = ei[j]; i1 = ei[E + j]; i2 = i0;
                w = -fmaxf(nw[i0], nw[i1]);
            } else {
                const int f = j - E;
                i0 = fc[f]; i1 = fc[F + f]; i2 = fc[2 * F + f];
                w = fmaxf(nw[i0], fmaxf(nw[i1], nw[i2]));
            }
            const int b = batch[i0];
            const int r = atomicAdd(&lc[b], 1);
            U[ebase[b] + lb[b] + r] = make_int4(i0, i1, i2, __float_as_int(w));
        }
    }
}

// ---------- main: stream graph-contiguous simplexes; per-wave private hist ----------
__global__ __launch_bounds__(256) void k_main2(
    const float* __restrict__ nh, const int4* __restrict__ U,
    const int* __restrict__ ubase, float* __restrict__ partial)
{
    __shared__ float hist[4][NROWS * 64];

    const int tid  = threadIdx.x;
    const int wave = tid >> 6;
    const int lane = tid & 63;
    const int t    = lane & 31;
    const int half = lane >> 5;
    const int b     = blockIdx.x & 63;      // XCD-aligned: all chunks of b on XCD b%8
    const int chunk = blockIdx.x >> 6;

    float* H = hist[wave];
    for (int i = tid; i < 4 * NROWS * 64; i += 256) ((float*)hist)[i] = 0.0f;
    __syncthreads();

    const float INV = 31.0f / 2.2f;
    const float DLT = 2.2f / 31.0f;

    const int g0 = ubase[b], g1 = ubase[b + 1];
    const int gc = g1 - g0;
    const int m0 = g0 + (int)(((long long)gc * chunk) / NC);
    const int m1 = g0 + (int)(((long long)gc * (chunk + 1)) / NC);

    for (int k = m0 + wave * 2; k < m1; k += 8) {
        const int kk = k + half;
        const bool valid = (kk < m1);
        const int4 q = U[valid ? kk : k];
        const float h = fminf(nh[q.x * 32 + t],
                        fminf(nh[q.y * 32 + t], nh[q.z * 32 + t]));
        const float w = __int_as_float(q.w);
        if (valid) {
            // s* = rint((h+R)/step); sigma* = 1/(1+exp(500*(h - lin[s*])))
            const float hr = h + RADIUSF;
            float sf = rintf(hr * INV);
            sf = fminf(fmaxf(sf, 0.0f), 32.0f);
            const float t1 = __builtin_fmaf(sf, -DLT, hr);   // h - lin[s*]
            const float Ee = __expf(500.0f * t1);
            const float sg = __builtin_amdgcn_rcpf(1.0f + Ee);
            const float dA = w * sg;
            const float dB = w - dA;
            float* p = H + (int)sf * 64 + lane;
            p[0]  += dA;
            p[64] += dB;
        }
    }

    __syncthreads();
    // flush rows 0..31 (rows 32/33 are beyond the output prefix range)
    float* dst = partial + ((size_t)blockIdx.x << 10);
    for (int i = tid; i < SS * TT; i += 256) {
        const int s = i >> 5, t2 = i & 31;
        float acc = 0.0f;
#pragma unroll
        for (int wv = 0; wv < 4; ++wv)
            acc += hist[wv][s * 64 + t2] + hist[wv][s * 64 + t2 + 32];
        dst[i] = acc;
    }
}

// ---------- finish: one block per graph; reduce chunks + prefix over s ----------
__global__ __launch_bounds__(1024) void k_finish(
    const float* __restrict__ partial, float* __restrict__ out)
{
    __shared__ float tile[SS * TT];
    const int b   = blockIdx.x;
    const int tid = threadIdx.x;            // cell = s*32 + t
    float acc = 0.0f;
#pragma unroll
    for (int c = 0; c < NC; ++c) acc += partial[(((size_t)(c * NB + b)) << 10) + tid];
    tile[tid] = acc;
    __syncthreads();
    const int t = tid & 31, s = tid >> 5;
    float run = 0.0f;
    for (int sp = 0; sp <= s; ++sp) run += tile[(sp << 5) + t];
    out[((size_t)b << 10) + tid] = run;
}

extern "C" void kernel_launch(void* const* d_in, const int* in_sizes, int n_in,
                              void* d_out, int out_size, void* d_ws, size_t ws_size,
                              hipStream_t stream)
{
    const float* x     = (const float*)d_in[0];
    const float* nw    = (const float*)d_in[1];
    const float* v     = (const float*)d_in[2];
    const int*   ei    = (const int*)d_in[4];
    const int*   fc    = (const int*)d_in[5];
    const int*   batch = (const int*)d_in[6];
    float*       out   = (float*)d_out;

    const int Nn = in_sizes[1];
    const int E  = in_sizes[4] / 2;
    const int F  = in_sizes[5] / 3;
    const int M  = Nn + E + F;

    auto align256 = [](size_t v_) { return (v_ + 255) & ~(size_t)255; };
    const size_t nh_b   = align256((size_t)Nn * TT * sizeof(float));     // 6.4 MB
    const size_t U_b    = align256((size_t)M * sizeof(int4));            // 3.7 MB
    const size_t part_b = align256((size_t)NC * NB * SS * TT * sizeof(float)); // 4 MB
    const size_t misc_o = nh_b + U_b + part_b;

    float* nh      = (float*)d_ws;
    int4*  U       = (int4*)((char*)d_ws + nh_b);
    float* partial = (float*)((char*)d_ws + nh_b + U_b);
    int*   gcnt    = (int*)((char*)d_ws + misc_o);             // [64]
    int*   cur     = gcnt + 64;                                // [64]
    int*   ns      = cur + 64;                                 // [65]
    int*   ubase   = ns + 72;                                  // [65]
    int*   ebase   = ubase + 72;                               // [64]

    hipMemsetAsync(gcnt, 0, NB * sizeof(int), stream);
    k_nh     <<<(Nn * TT + 255) / 256, 256, 0, stream>>>(x, v, nh, Nn);
    k_count  <<<NCNT, 256, 0, stream>>>(ei, fc, batch, gcnt, E, F);
    k_prefix <<<1, 256, 0, stream>>>(batch, gcnt, ns, ubase, ebase, cur, Nn);
    k_scatter<<<NCNT, 256, 0, stream>>>(nw, ei, fc, batch, ns, ubase, ebase, cur, U, Nn, E, F);
    k_main2  <<<NC * NB, 256, 0, stream>>>(nh, U, ubase, partial);
    k_finish <<<NB, 1024, 0, stream>>>(partial, out);
}

// Round 9
// 65.577 us; speedup vs baseline: 2.9631x; 1.1108x over previous
//
#include <hip/hip_runtime.h>

// Problem constants: N=50000, E=100000, F=80000, B=64, S=32, T=32, D=3
#define NB      64
#define SS      32
#define TT      32
#define RADIUSF 1.1f
#define NC      16              // chunks per graph -> grid = 16*64 = 1024 = 4 blocks/CU
#define NROWS   34              // delta bins: s* in [0,32], s*+1 in [1,33]
#define NCNT    128             // blocks for count/scatter passes

// ---------- fused: node heights nh[n*32+t]  +  per-block E/F bucket counts ----------
__global__ __launch_bounds__(256) void k_pre(
    const float* __restrict__ x, const float* __restrict__ v,
    const int* __restrict__ ei, const int* __restrict__ fc,
    const int* __restrict__ batch,
    float* __restrict__ nh, int* __restrict__ cntp,
    int Nn, int E, int F, int nhBlocks)
{
    const int tid = threadIdx.x;
    if ((int)blockIdx.x < nhBlocks) {
        const int idx = blockIdx.x * 256 + tid;
        if (idx >= Nn * TT) return;
        const int n = idx >> 5, t = idx & 31;
        nh[idx] = x[3 * n] * v[t] + x[3 * n + 1] * v[TT + t] + x[3 * n + 2] * v[2 * TT + t];
    } else {
        __shared__ int lc[NB];
        const int blk = blockIdx.x - nhBlocks;      // 0..NCNT-1
        const int EF = E + F;
        if (tid < NB) lc[tid] = 0;
        __syncthreads();
        const int j0 = (int)((long long)EF * blk / NCNT);
        const int j1 = (int)((long long)EF * (blk + 1) / NCNT);
        for (int j = j0 + tid; j < j1; j += 256) {
            const int i0 = (j < E) ? ei[j] : fc[j - E];
            atomicAdd(&lc[batch[i0]], 1);           // LDS only
        }
        __syncthreads();
        if (tid < NB) cntp[blk * NB + tid] = lc[tid];   // plain store, no global atomics
    }
}

// ---------- prefix: node ranges + bucket bases (sums cntp); zero cur ----------
__global__ __launch_bounds__(256) void k_prefix(
    const int* __restrict__ batch, const int* __restrict__ cntp,
    int* __restrict__ ns, int* __restrict__ ubase, int* __restrict__ ebase,
    int* __restrict__ cur, int Nn)
{
    __shared__ int s_ns[NB + 1];
    __shared__ int s_sum[4][NB];
    __shared__ int s_base[NB + 1];
    const int tid = threadIdx.x;
    if (tid <= NB) {
        int lo = 0, hi = Nn;
        while (lo < hi) { const int mid = (lo + hi) >> 1; if (batch[mid] < tid) lo = mid + 1; else hi = mid; }
        s_ns[tid] = lo;
    }
    // sum cntp over NCNT blocks: quarter q sums 32 blocks for bucket b
    {
        const int b = tid & 63, q = tid >> 6;
        int s = 0;
        for (int blk = q * (NCNT / 4); blk < (q + 1) * (NCNT / 4); ++blk)
            s += cntp[blk * NB + b];
        s_sum[q][b] = s;
    }
    __syncthreads();
    if (tid == 0) {
        int run = 0;
        for (int b = 0; b < NB; ++b) {
            s_base[b] = run;
            run += s_sum[0][b] + s_sum[1][b] + s_sum[2][b] + s_sum[3][b];
        }
        s_base[NB] = run;
    }
    __syncthreads();
    if (tid <= NB) { ns[tid] = s_ns[tid]; ubase[tid] = s_ns[tid] + s_base[tid]; }
    if (tid < NB)  { ebase[tid] = s_ns[tid + 1] + s_base[tid]; cur[tid] = 0; }
}

// ---------- scatter: build unified graph-sorted simplex array U ----------
__global__ __launch_bounds__(256) void k_scatter(
    const float* __restrict__ nw, const int* __restrict__ ei,
    const int* __restrict__ fc, const int* __restrict__ batch,
    const int* __restrict__ ns, const int* __restrict__ ubase,
    const int* __restrict__ ebase, int* __restrict__ cur,
    int4* __restrict__ U, int Nn, int E, int F)
{
    __shared__ int lc[NB];
    __shared__ int lb[NB];
    const int tid = threadIdx.x;
    const int M = Nn + E + F;
    const int m0 = (int)((long long)M * blockIdx.x / gridDim.x);
    const int m1 = (int)((long long)M * (blockIdx.x + 1) / gridDim.x);
    if (tid < NB) lc[tid] = 0;
    __syncthreads();
    // pass A: write nodes directly (deterministic slots); count edges/faces
    for (int m = m0 + tid; m < m1; m += 256) {
        if (m < Nn) {
            const int b = batch[m];
            U[ubase[b] + (m - ns[b])] = make_int4(m, m, m, __float_as_int(nw[m]));
        } else {
            const int j = m - Nn;
            const int i0 = (j < E) ? ei[j] : fc[j - E];
            atomicAdd(&lc[batch[i0]], 1);
        }
    }
    __syncthreads();
    if (tid < NB) { const int c = lc[tid]; lb[tid] = c ? atomicAdd(&cur[tid], c) : 0; lc[tid] = 0; }
    __syncthreads();
    // pass B: write edges/faces at reserved slots
    for (int m = m0 + tid; m < m1; m += 256) {
        if (m >= Nn) {
            const int j = m - Nn;
            int i0, i1, i2; float w;
            if (j < E) {
                i0 = ei[j]; i1 = ei[E + j]; i2 = i0;
                w = -fmaxf(nw[i0], nw[i1]);
            } else {
                const int f = j - E;
                i0 = fc[f]; i1 = fc[F + f]; i2 = fc[2 * F + f];
                w = fmaxf(nw[i0], fmaxf(nw[i1], nw[i2]));
            }
            const int b = batch[i0];
            const int r = atomicAdd(&lc[b], 1);
            U[ebase[b] + lb[b] + r] = make_int4(i0, i1, i2, __float_as_int(w));
        }
    }
}

// ---------- main: stream graph-contiguous simplexes; per-wave private hist ----------
__global__ __launch_bounds__(256) void k_main2(
    const float* __restrict__ nh, const int4* __restrict__ U,
    const int* __restrict__ ubase, float* __restrict__ partial)
{
    __shared__ float hist[4][NROWS * 64];

    const int tid  = threadIdx.x;
    const int wave = tid >> 6;
    const int lane = tid & 63;
    const int t    = lane & 31;
    const int half = lane >> 5;
    const int b     = blockIdx.x & 63;      // XCD-aligned: all chunks of b on XCD b%8
    const int chunk = blockIdx.x >> 6;

    float* H = hist[wave];
    for (int i = tid; i < 4 * NROWS * 64; i += 256) ((float*)hist)[i] = 0.0f;
    __syncthreads();

    const float INV = 31.0f / 2.2f;
    const float DLT = 2.2f / 31.0f;

    const int g0 = ubase[b], g1 = ubase[b + 1];
    const int gc = g1 - g0;
    const int m0 = g0 + (int)(((long long)gc * chunk) / NC);
    const int m1 = g0 + (int)(((long long)gc * (chunk + 1)) / NC);

    for (int k = m0 + wave * 2; k < m1; k += 8) {
        const int kk = k + half;
        const bool valid = (kk < m1);
        const int4 q = U[valid ? kk : k];
        const float h = fminf(nh[q.x * 32 + t],
                        fminf(nh[q.y * 32 + t], nh[q.z * 32 + t]));
        const float w = __int_as_float(q.w);
        if (valid) {
            // s* = rint((h+R)/step); sigma* = 1/(1+exp(500*(h - lin[s*])))
            const float hr = h + RADIUSF;
            float sf = rintf(hr * INV);
            sf = fminf(fmaxf(sf, 0.0f), 32.0f);
            const float t1 = __builtin_fmaf(sf, -DLT, hr);   // h - lin[s*]
            const float Ee = __expf(500.0f * t1);
            const float sg = __builtin_amdgcn_rcpf(1.0f + Ee);
            const float dA = w * sg;
            const float dB = w - dA;
            float* p = H + (int)sf * 64 + lane;
            p[0]  += dA;
            p[64] += dB;
        }
    }

    __syncthreads();
    // flush rows 0..31 (rows 32/33 are beyond the output prefix range)
    float* dst = partial + ((size_t)blockIdx.x << 10);
    for (int i = tid; i < SS * TT; i += 256) {
        const int s = i >> 5, t2 = i & 31;
        float acc = 0.0f;
#pragma unroll
        for (int wv = 0; wv < 4; ++wv)
            acc += hist[wv][s * 64 + t2] + hist[wv][s * 64 + t2 + 32];
        dst[i] = acc;
    }
}

// ---------- finish: one block per graph; reduce chunks + prefix over s ----------
__global__ __launch_bounds__(1024) void k_finish(
    const float* __restrict__ partial, float* __restrict__ out)
{
    __shared__ float tile[SS * TT];
    const int b   = blockIdx.x;
    const int tid = threadIdx.x;            // cell = s*32 + t
    float acc = 0.0f;
#pragma unroll
    for (int c = 0; c < NC; ++c) acc += partial[(((size_t)(c * NB + b)) << 10) + tid];
    tile[tid] = acc;
    __syncthreads();
    const int t = tid & 31, s = tid >> 5;
    float run = 0.0f;
    for (int sp = 0; sp <= s; ++sp) run += tile[(sp << 5) + t];
    out[((size_t)b << 10) + tid] = run;
}

extern "C" void kernel_launch(void* const* d_in, const int* in_sizes, int n_in,
                              void* d_out, int out_size, void* d_ws, size_t ws_size,
                              hipStream_t stream)
{
    const float* x     = (const float*)d_in[0];
    const float* nw    = (const float*)d_in[1];
    const float* v     = (const float*)d_in[2];
    const int*   ei    = (const int*)d_in[4];
    const int*   fc    = (const int*)d_in[5];
    const int*   batch = (const int*)d_in[6];
    float*       out   = (float*)d_out;

    const int Nn = in_sizes[1];
    const int E  = in_sizes[4] / 2;
    const int F  = in_sizes[5] / 3;
    const int M  = Nn + E + F;

    auto align256 = [](size_t v_) { return (v_ + 255) & ~(size_t)255; };
    const size_t nh_b   = align256((size_t)Nn * TT * sizeof(float));     // 6.4 MB
    const size_t U_b    = align256((size_t)M * sizeof(int4));            // 3.7 MB
    const size_t part_b = align256((size_t)NC * NB * SS * TT * sizeof(float)); // 4 MB
    const size_t misc_o = nh_b + U_b + part_b;

    float* nh      = (float*)d_ws;
    int4*  U       = (int4*)((char*)d_ws + nh_b);
    float* partial = (float*)((char*)d_ws + nh_b + U_b);
    int*   cntp    = (int*)((char*)d_ws + misc_o);             // [NCNT*64]
    int*   cur     = cntp + NCNT * NB;                         // [64]
    int*   ns      = cur + 64;                                 // [65]
    int*   ubase   = ns + 72;                                  // [65]
    int*   ebase   = ubase + 72;                               // [64]

    const int nhBlocks = (Nn * TT + 255) / 256;
    k_pre    <<<nhBlocks + NCNT, 256, 0, stream>>>(x, v, ei, fc, batch, nh, cntp,
                                                   Nn, E, F, nhBlocks);
    k_prefix <<<1, 256, 0, stream>>>(batch, cntp, ns, ubase, ebase, cur, Nn);
    k_scatter<<<NCNT, 256, 0, stream>>>(nw, ei, fc, batch, ns, ubase, ebase, cur, U, Nn, E, F);
    k_main2  <<<NC * NB, 256, 0, stream>>>(nh, U, ubase, partial);
    k_finish <<<NB, 1024, 0, stream>>>(partial, out);
}